// Round 1
// 1137.578 us; speedup vs baseline: 1.0832x; 1.0832x over previous
//
#include <hip/hip_runtime.h>
#include <math.h>

typedef __bf16 bf16;
typedef __attribute__((ext_vector_type(8))) __bf16 bf16x8;
typedef __attribute__((ext_vector_type(4))) __bf16 bf16x4;
typedef __attribute__((ext_vector_type(2))) __bf16 bf16x2;
typedef __attribute__((ext_vector_type(4))) float f32x4;

#define DIM 2048
#define NH 16
#define DKK 128
#define BATCH 4
#define SEQ 4096
#define BN (BATCH*SEQ)
#define INV_SQRT_DK 0.08838834764831845f

#define MFMA16(a,b,c) __builtin_amdgcn_mfma_f32_16x16x32_bf16((a),(b),(c),0,0,0)

#define GLDS(gp, lp) __builtin_amdgcn_global_load_lds( \
    (const __attribute__((address_space(1))) void*)(gp), \
    (__attribute__((address_space(3))) void*)(lp), 16, 0, 0)

// stage a (32*nwaves)x64 bf16 tile (row stride ld in global) into LDS
// (stride 64, chunk-XOR swizzle). Each wave stages rows [wave*32, wave*32+32).
// 4 GLDS per thread per call.
__device__ inline void stage_tile(const bf16* __restrict__ g, int ld,
                                  bf16* lds, int lane, int wave) {
  const int rl = lane >> 3;                      // 0..7 row within 8-row group
  const int gc = ((lane & 7) ^ (rl & 7)) << 3;   // swizzled source chunk (elements)
  const bf16* gp = g + (size_t)(wave * 32 + rl) * ld + gc;
#pragma unroll
  for (int t = 0; t < 4; ++t)
    GLDS(gp + (size_t)(t * 8) * ld, lds + (wave * 32 + t * 8) * 64);
}

// read 8 consecutive (global-k) elements for row r at global chunk kc from a swizzled 64-stride tile
__device__ inline bf16x8 frag8(const bf16* lds, int r, int kc) {
  return *(const bf16x8*)(lds + r * 64 + (((kc ^ (r & 7)) << 3)));
}

// scalar element address in swizzled 64-stride tile
__device__ inline int sq64(int r, int c) {
  return r * 64 + ((((c >> 3) ^ (r & 7)) << 3) | (c & 7));
}

__device__ inline float fast_exp(float x) { return __expf(x); }
__device__ inline float fast_tanh(float x) {
  float e2 = __expf(2.f * x);
  return 1.f - 2.f / (e2 + 1.f);
}

// ---------------- conversion kernels ----------------
__global__ __launch_bounds__(256) void conv_bf16(const float* __restrict__ x,
                                                 bf16* __restrict__ y) {
  int i = (blockIdx.x * 256 + threadIdx.x) * 4;
  float4 v = *(const float4*)(x + i);
  bf16x4 o = { (bf16)v.x, (bf16)v.y, (bf16)v.z, (bf16)v.w };
  *(bf16x4*)(y + i) = o;
}

// 3 fused 2048x2048 transposes selected by blockIdx.z (Wk, Wv, Wo)
__global__ __launch_bounds__(256) void tconv3(const float* W0, const float* W1,
                                              const float* W2,
                                              bf16* O0, bf16* O1, bf16* O2) {
  __shared__ float tile[32][33];
  const float* Wp; bf16* Op;
  switch (blockIdx.z) {
    case 0: Wp = W0; Op = O0; break;
    case 1: Wp = W1; Op = O1; break;
    default: Wp = W2; Op = O2; break;
  }
  int c0 = blockIdx.x * 32, r0 = blockIdx.y * 32;
  int tx = threadIdx.x, ty = threadIdx.y;  // (32,8)
#pragma unroll
  for (int i = 0; i < 4; ++i)
    tile[ty + i*8][tx] = Wp[(size_t)(r0 + ty + i*8) * DIM + c0 + tx];
  __syncthreads();
#pragma unroll
  for (int i = 0; i < 4; ++i)
    Op[(size_t)(c0 + ty + i*8) * DIM + r0 + tx] = (bf16)tile[tx][ty + i*8];
}

// per-head 128x128 transpose for W_bilinear
__global__ __launch_bounds__(256) void tconvWb(const float* __restrict__ W,
                                               bf16* __restrict__ Wt) {
  __shared__ float tile[32][33];
  const float* Wp = W + (size_t)blockIdx.z * DKK * DKK;
  bf16* Wtp = Wt + (size_t)blockIdx.z * DKK * DKK;
  int c0 = blockIdx.x * 32, r0 = blockIdx.y * 32;
  int tx = threadIdx.x, ty = threadIdx.y;
#pragma unroll
  for (int i = 0; i < 4; ++i)
    tile[ty + i*8][tx] = Wp[(size_t)(r0 + ty + i*8) * DKK + c0 + tx];
  __syncthreads();
#pragma unroll
  for (int i = 0; i < 4; ++i)
    Wtp[(size_t)(c0 + ty + i*8) * DKK + r0 + tx] = (bf16)tile[tx][ty + i*8];
}

// rbuf[h][n] = exp((fs[h]-ss[h])*(n-(SEQ-1)))
__global__ __launch_bounds__(256) void rweights(const float* __restrict__ fs,
                                                const float* __restrict__ ss,
                                                float* __restrict__ rbuf) {
  int n = blockIdx.x * 256 + threadIdx.x;
  int h = blockIdx.y;
  rbuf[h * SEQ + n] = fast_exp((fs[h] - ss[h]) * (float)(n - (SEQ - 1)));
}

// ---------------- mean + MLP (psi) ----------------
__global__ void zero_f32(float* p, int n) {
  int i = blockIdx.x * 256 + threadIdx.x;
  if (i < n) p[i] = 0.f;
}

__global__ __launch_bounds__(256) void mean_part(const bf16* __restrict__ xb,
                                                 float* __restrict__ xm) {
  int d0 = (blockIdx.x * 256 + threadIdx.x) * 2;
  int b = blockIdx.z;
  const bf16* xp = xb + ((size_t)b * SEQ + (size_t)blockIdx.y * 256) * DIM + d0;
  float s0 = 0.f, s1 = 0.f;
#pragma unroll 8
  for (int n = 0; n < 256; ++n) {
    bf16x2 v = *(const bf16x2*)(xp + (size_t)n * DIM);
    s0 += (float)v[0]; s1 += (float)v[1];
  }
  atomicAdd(&xm[b * DIM + d0], s0);
  atomicAdd(&xm[b * DIM + d0 + 1], s1);
}

// partial dot over k-split; h1raw accumulates raw (unscaled) sums
__global__ __launch_bounds__(256) void mlp1(const float* __restrict__ xm,
                                            const float* __restrict__ f1w,
                                            float* __restrict__ h1raw) {
  int j = blockIdx.x * 256 + threadIdx.x;   // 0..1023
  int b = blockIdx.y;
  int k0 = blockIdx.z * 256;
  const float* xmb = xm + b * DIM + k0;
  const float* w = f1w + (size_t)k0 * (DIM/2) + j;
  float s = 0.f;
#pragma unroll 4
  for (int k = 0; k < 256; ++k) s += xmb[k] * w[(size_t)k * (DIM/2)];
  atomicAdd(&h1raw[b * (DIM/2) + j], s);
}

__global__ void mlp2(const float* __restrict__ h1raw,
                     const float* __restrict__ f1b,
                     const float* __restrict__ f2w,
                     const float* __restrict__ f2b,
                     float* __restrict__ psi_out) {
  int t = threadIdx.x;  // 64 threads
  int b = t >> 4, h = t & 15;
  float s = f2b[h];
  for (int k = 0; k < DIM/2; ++k) {
    float hv = h1raw[b * (DIM/2) + k] * (1.f / (float)SEQ) + f1b[k];
    hv = hv / (1.f + fast_exp(-hv));          // silu
    s += hv * f2w[k * NH + h];
  }
  psi_out[t] = 1.f / (1.f + fast_exp(-s));    // sigmoid
}

// ---------------- 256x256 pipelined GEMM: C(MxN) = A(MxK) @ Bt(NxK)^T ----------------
// 8 waves (512 thr), BK=64, 2x LDS buffers (128 KiB), counted-vmcnt pipeline:
// per K-tile: issue next tile's 8 GLDS -> s_waitcnt vmcnt(8) -> s_barrier ->
// 64 MFMA/wave (setprio-wrapped) -> s_barrier. Loads are never drained to 0
// inside the loop (T3+T4); chunk-XOR LDS swizzle keeps ds_read_b128 2-way (free).
// MODE 2: bf16 transposed per-head store (vt).
// MODE 3: f32 normal out, Bt per-batch (+= (m0>>12)*DIM*DIM)  [final: out = x @ Wcomb[b]]
// MODE 4: bf16 normal out, A and C per-batch (2048 rows each)  [Wcombt[b] = W2t[b] @ Wq^T]
// MODE 5: bf16 normal out (row-major MxN)                      [kn = x @ Wk]
template<int MODE>
__global__ __launch_bounds__(512, 2) void gemm256(const bf16* __restrict__ A, int lda,
                                                  const bf16* __restrict__ Bt, int ldb,
                                                  void* __restrict__ Cv, int ldc, int K) {
  __shared__ bf16 smem[65536];   // [2 buf][ A 256x64 | B 256x64 ] = 128 KiB
  const int tid = threadIdx.x;
  const int lane = tid & 63;
  const int wave = tid >> 6;          // 0..7
  const int quad = lane >> 4;
  const int l15 = lane & 15;
  const int wm = (wave >> 2) * 128;   // 2 row-waves x 128 rows
  const int wn = (wave & 3) * 64;     // 4 col-waves x 64 cols
  const size_t m0 = (size_t)blockIdx.y * 256;
  const size_t n0 = (size_t)blockIdx.x * 256;
  const bf16* Ap = A;
  const bf16* Bp = Bt;
  size_t mrow = m0;
  size_t cbat = 0;
  if (MODE == 3) Bp += (size_t)(m0 >> 12) * DIM * DIM;
  if (MODE == 4) {
    size_t b = m0 >> 11;              // 2048 rows per batch
    Ap += b * (size_t)DIM * DIM;
    cbat = b * (size_t)DIM * DIM;
    mrow = m0 & 2047;
  }
  const bf16* Arow = Ap + mrow * (size_t)lda;
  const bf16* Brow = Bp + n0 * (size_t)ldb;
  f32x4 acc[8][4] = {};
  const int NT = K >> 6;
  // prologue: stage tile 0 into buffer 0  (8 GLDS per thread)
  stage_tile(Arow, lda, smem, lane, wave);
  stage_tile(Brow, ldb, smem + 32768, lane, wave);
  for (int kt = 0; kt < NT; ++kt) {
    const int cur = kt & 1;
    const bf16* sA = smem + cur * 16384;
    const bf16* sB = smem + 32768 + cur * 16384;
    if (kt + 1 < NT) {
      const int nxt = cur ^ 1;
      const int k0 = (kt + 1) << 6;
      stage_tile(Arow + k0, lda, smem + nxt * 16384, lane, wave);
      stage_tile(Brow + k0, ldb, smem + 32768 + nxt * 16384, lane, wave);
      // 16 GLDS outstanding: wait current tile's 8, keep next tile's 8 in flight
      asm volatile("s_waitcnt vmcnt(8)\n\ts_barrier" ::: "memory");
    } else {
      asm volatile("s_waitcnt vmcnt(0)\n\ts_barrier" ::: "memory");
    }
    bf16x8 bfr[2][4];
#pragma unroll
    for (int kk = 0; kk < 2; ++kk)
#pragma unroll
      for (int j = 0; j < 4; ++j)
        bfr[kk][j] = frag8(sB, wn + j * 16 + l15, kk * 4 + quad);
#pragma unroll
    for (int i2 = 0; i2 < 4; ++i2) {
      bf16x8 af[2][2];
#pragma unroll
      for (int ii = 0; ii < 2; ++ii)
#pragma unroll
        for (int kk = 0; kk < 2; ++kk)
          af[ii][kk] = frag8(sA, wm + (i2 * 2 + ii) * 16 + l15, kk * 4 + quad);
      __builtin_amdgcn_s_setprio(1);
#pragma unroll
      for (int ii = 0; ii < 2; ++ii)
#pragma unroll
        for (int j = 0; j < 4; ++j) {
          acc[i2*2+ii][j] = MFMA16(af[ii][0], bfr[0][j], acc[i2*2+ii][j]);
          acc[i2*2+ii][j] = MFMA16(af[ii][1], bfr[1][j], acc[i2*2+ii][j]);
        }
      __builtin_amdgcn_s_setprio(0);
    }
    asm volatile("s_barrier" ::: "memory");
  }
  // ---------------- epilogues ----------------
  if (MODE == 2) {
    // transposed per-head store: vt[(b*NH+h)*DKK + dv][nseq]
    const int bb = (int)(m0 >> 12);
    const int nb0 = (int)(m0 & 4095) + wm + quad * 4;
    bf16* vt = (bf16*)Cv;
#pragma unroll
    for (int i = 0; i < 8; ++i)
#pragma unroll
      for (int j = 0; j < 4; ++j) {
        int colg = (int)n0 + wn + j * 16 + l15;
        int h = colg >> 7, dv = colg & 127;
        bf16x4 p = { (bf16)acc[i][j][0], (bf16)acc[i][j][1],
                     (bf16)acc[i][j][2], (bf16)acc[i][j][3] };
        *(bf16x4*)(vt + ((size_t)(bb * NH + h) * DKK + dv) * SEQ + nb0 + i * 16) = p;
      }
  } else {
#pragma unroll
    for (int i = 0; i < 8; ++i)
#pragma unroll
      for (int j = 0; j < 4; ++j) {
        size_t col = n0 + wn + j * 16 + l15;
        size_t row = mrow + wm + i * 16 + quad * 4;
#pragma unroll
        for (int r = 0; r < 4; ++r) {
          if (MODE == 3) ((float*)Cv)[(row + r) * ldc + col] = acc[i][j][r];
          else           ((bf16*)Cv)[cbat + (row + r) * ldc + col] = (bf16)acc[i][j][r];
        }
      }
  }
}

// ---------------- resonance + k_mod + transposed slow-weighted store ----------------
// R[n][e] = sum_d kn[b,n][h*128+d] * Wbt[h][e][d]   (K=128, per (bh, n-tile of 128))
// kts[(bh)*DKK + e][n] = kn[n][e] * (1+0.5*tanh(R[n][e])) * inv_sqrt_dk * exp(ss*(n-(SEQ-1)))
__global__ __launch_bounds__(256) void res_fuse(const bf16* __restrict__ kn,
                                                const bf16* __restrict__ Wbt,
                                                const float* __restrict__ slow_slope,
                                                bf16* __restrict__ kts) {
  __shared__ bf16 sA2[2][8192];   // both 64-chunks of the kn tile (kept for epilogue)
  __shared__ bf16 sB[8192];
  const int tid = threadIdx.x;
  const int lane = tid & 63;
  const int wave = tid >> 6;
  const int quad = lane >> 4;
  const int l15 = lane & 15;
  const int wm = (wave & 1) * 64;
  const int wn = (wave >> 1) * 64;
  const int nt = blockIdx.x;              // 0..31 (n-tile within batch)
  const int bh = blockIdx.y;              // 0..63
  const int h = bh & (NH - 1), b = bh >> 4;
  const bf16* Ap = kn + ((size_t)b * SEQ + (size_t)nt * 128) * DIM + h * DKK;
  const bf16* Bp = Wbt + (size_t)h * DKK * DKK;
  const float ss = slow_slope[h];
  f32x4 acc[4][4] = {};
#pragma unroll
  for (int c = 0; c < 2; ++c) {
    stage_tile(Ap + c * 64, DIM, sA2[c], lane, wave);
    stage_tile(Bp + c * 64, DKK, sB, lane, wave);
    __syncthreads();
#pragma unroll
    for (int kk = 0; kk < 2; ++kk) {
      const int kc = kk * 4 + quad;
      bf16x8 af[4], bfr[4];
#pragma unroll
      for (int i = 0; i < 4; ++i) af[i] = frag8(sA2[c], wm + i*16 + l15, kc);
#pragma unroll
      for (int j = 0; j < 4; ++j) bfr[j] = frag8(sB, wn + j*16 + l15, kc);
#pragma unroll
      for (int i = 0; i < 4; ++i)
#pragma unroll
        for (int j = 0; j < 4; ++j)
          acc[i][j] = MFMA16(af[i], bfr[j], acc[i][j]);
    }
    __syncthreads();
  }
  float wsv[4][4];
#pragma unroll
  for (int i = 0; i < 4; ++i)
#pragma unroll
    for (int r = 0; r < 4; ++r) {
      int ng = nt * 128 + wm + i*16 + quad*4 + r;
      wsv[i][r] = fast_exp(ss * (float)(ng - (SEQ - 1)));
    }
#pragma unroll
  for (int i = 0; i < 4; ++i)
#pragma unroll
    for (int j = 0; j < 4; ++j) {
      int e = wn + j*16 + l15;
      const bf16* sAe = sA2[e >> 6];
      int ec = e & 63;
      bf16x4 p;
#pragma unroll
      for (int r = 0; r < 4; ++r) {
        int nl = wm + i*16 + quad*4 + r;
        float kv = (float)sAe[sq64(nl, ec)];
        float res = fast_tanh(acc[i][j][r]);
        p[r] = (bf16)(kv * (1.f + 0.5f * res) * INV_SQRT_DK * wsv[i][r]);
      }
      *(bf16x4*)(kts + ((size_t)bh * DKK + e) * SEQ + nt * 128 + wm + i*16 + quad*4) = p;
    }
}

// ---------------- mcurr: partials[s][bh][{fast,slow}] = Kt(diag w)V over n-split ----------------
__global__ __launch_bounds__(256) void mcurr(const bf16* __restrict__ kts,
                                             const bf16* __restrict__ vt,
                                             const float* __restrict__ rbuf,
                                             float* __restrict__ partials) {
  __shared__ bf16 sK[128 * 64];
  __shared__ bf16 sV[128 * 64];
  const int tid = threadIdx.x;
  const int lane = tid & 63;
  const int wave = tid >> 6;
  const int quad = lane >> 4;
  const int wm = (wave & 1) * 64, wn = (wave >> 1) * 64;
  const int s = blockIdx.x;          // 0..7
  const int bh = blockIdx.y;         // 0..63
  const int h = bh & (NH - 1);
  const bf16* Ap = kts + (size_t)bh * DKK * SEQ;
  const bf16* Bp = vt + (size_t)bh * DKK * SEQ;
  const float* rp = rbuf + (size_t)h * SEQ;
  f32x4 accF[4][4] = {}, accS[4][4] = {};
  for (int k0 = s * 512; k0 < s * 512 + 512; k0 += 64) {
    stage_tile(Ap + k0, SEQ, sK, lane, wave);
    stage_tile(Bp + k0, SEQ, sV, lane, wave);
    __syncthreads();
#pragma unroll
    for (int kk = 0; kk < 2; ++kk) {
      const int kc = kk * 4 + quad;
      const int kn_ = k0 + kc * 8;
      float rv[8];
      *(f32x4*)rv       = *(const f32x4*)(rp + kn_);
      *(f32x4*)(rv + 4) = *(const f32x4*)(rp + kn_ + 4);
      bf16x8 afS[4], afF[4], bfv[4];
#pragma unroll
      for (int i = 0; i < 4; ++i) afS[i] = frag8(sK, wm + i*16 + (lane & 15), kc);
#pragma unroll
      for (int j = 0; j < 4; ++j) bfv[j] = frag8(sV, wn + j*16 + (lane & 15), kc);
#pragma unroll
      for (int i = 0; i < 4; ++i)
#pragma unroll
        for (int e = 0; e < 8; ++e)
          afF[i][e] = (bf16)((float)afS[i][e] * rv[e]);
#pragma unroll
      for (int i = 0; i < 4; ++i)
#pragma unroll
        for (int j = 0; j < 4; ++j) {
          accS[i][j] = MFMA16(afS[i], bfv[j], accS[i][j]);
          accF[i][j] = MFMA16(afF[i], bfv[j], accF[i][j]);
        }
    }
    __syncthreads();
  }
  float* Pf = partials + ((size_t)(s * 64 + bh) * 2 + 0) * (DKK * DKK);
  float* Ps = partials + ((size_t)(s * 64 + bh) * 2 + 1) * (DKK * DKK);
#pragma unroll
  for (int i = 0; i < 4; ++i)
#pragma unroll
    for (int j = 0; j < 4; ++j) {
      int col = wn + j*16 + (lane & 15);
      int row = wm + i*16 + quad * 4;
#pragma unroll
      for (int r = 0; r < 4; ++r) {
        Pf[(row + r) * DKK + col] = accF[i][j][r];
        Ps[(row + r) * DKK + col] = accS[i][j][r];
      }
    }
}

// ---------------- finalize: M update, (I+S)@M, blend -> Mb (normal order, bf16) ----------------
__global__ __launch_bounds__(256) void finalize(const float* __restrict__ partials,
                                                const float* __restrict__ Mf_prev,
                                                const float* __restrict__ Ms_prev,
                                                const float* __restrict__ inter_fast,
                                                const float* __restrict__ inter_slow,
                                                const float* __restrict__ S_fast,
                                                const float* __restrict__ S_slow,
                                                const float* __restrict__ psi,
                                                float* __restrict__ Mf_out,
                                                float* __restrict__ Ms_out,
                                                bf16* __restrict__ Mb) {
  __shared__ float sMf[128 * 33];
  __shared__ float sMs[128 * 33];
  const int t = threadIdx.x;
  const int bh = blockIdx.x;
  const int h = bh & (NH - 1);
  const int e0 = blockIdx.y * 32;
  const int el = t & 31;
  const int d0 = t >> 5;  // 0..7
  const float inf_ = inter_fast[h], ins_ = inter_slow[h];
  const size_t mb = (size_t)bh * (DKK * DKK);
#pragma unroll
  for (int i = 0; i < 16; ++i) {
    int d = d0 + 8 * i;
    int g = d * DKK + e0 + el;
    float mf = inf_ * Mf_prev[mb + g];
    float ms = ins_ * Ms_prev[mb + g];
#pragma unroll
    for (int s = 0; s < 8; ++s) {
      mf += partials[((size_t)(s * 64 + bh) * 2 + 0) * (DKK*DKK) + g];
      ms += partials[((size_t)(s * 64 + bh) * 2 + 1) * (DKK*DKK) + g];
    }
    Mf_out[mb + g] = mf;
    Ms_out[mb + g] = ms;
    sMf[d * 33 + el] = mf;
    sMs[d * 33 + el] = ms;
  }
  __syncthreads();
  const float p = psi[bh];
  for (int i = 0; i < 16; ++i) {
    int d = d0 + 8 * i;
    float accf = sMf[d * 33 + el];
    float accs = sMs[d * 33 + el];
    const float* Sf = S_fast + (size_t)h * (DKK*DKK) + (size_t)d * DKK;
    const float* Ss = S_slow + (size_t)h * (DKK*DKK) + (size_t)d * DKK;
    for (int k = 0; k < DKK; ++k) {
      accf += Sf[k] * sMf[k * 33 + el];
      accs += Ss[k] * sMs[k * 33 + el];
    }
    float blend = (1.f - p) * accf + p * accs;
    Mb[mb + (size_t)d * DKK + e0 + el] = (bf16)blend;   // Mb[dk][dv]
  }
}

// ---------------- w2: W2t[b][c][h*128+dk] = sum_dv Mb[b,h][dk,dv] * Wo[h*128+dv][c] ----------------
__global__ __launch_bounds__(256) void w2_gemm(const bf16* __restrict__ Mb,
                                               const bf16* __restrict__ Wto,
                                               bf16* __restrict__ W2t) {
  __shared__ bf16 sA[128 * 64];
  __shared__ bf16 sB[128 * 64];
  const int tid = threadIdx.x;
  const int lane = tid & 63;
  const int wave = tid >> 6;
  const int quad = lane >> 4;
  const int wm = (wave & 1) * 64, wn = (wave >> 1) * 64;
  const int c0 = blockIdx.x * 128;
  const int bh = blockIdx.y;
  const int h = bh & (NH - 1), b = bh >> 4;
  const bf16* Ap = Mb + (size_t)bh * DKK * DKK;
  const bf16* Bp = Wto + (size_t)c0 * DIM + h * DKK;
  f32x4 acc[4][4] = {};
#pragma unroll
  for (int k0 = 0; k0 < DKK; k0 += 64) {
    stage_tile(Ap + k0, DKK, sA, lane, wave);
    stage_tile(Bp + k0, DIM, sB, lane, wave);
    __syncthreads();
#pragma unroll
    for (int kk = 0; kk < 2; ++kk) {
      const int kc = kk * 4 + quad;
      bf16x8 af[4], bfr[4];
#pragma unroll
      for (int i = 0; i < 4; ++i) af[i] = frag8(sA, wm + i*16 + (lane & 15), kc);
#pragma unroll
      for (int j = 0; j < 4; ++j) bfr[j] = frag8(sB, wn + j*16 + (lane & 15), kc);
#pragma unroll
      for (int i = 0; i < 4; ++i)
#pragma unroll
        for (int j = 0; j < 4; ++j)
          acc[i][j] = MFMA16(af[i], bfr[j], acc[i][j]);
    }
    __syncthreads();
  }
  // transposed store: W2t[b] + (c0+col)*DIM + h*128 + row   (pack 4 rows)
  bf16* base = W2t + (size_t)b * DIM * DIM + h * DKK;
#pragma unroll
  for (int i = 0; i < 4; ++i)
#pragma unroll
    for (int j = 0; j < 4; ++j) {
      int col = wn + j*16 + (lane & 15);
      int row0 = wm + i*16 + quad * 4;
      bf16x4 p = { (bf16)acc[i][j][0], (bf16)acc[i][j][1],
                   (bf16)acc[i][j][2], (bf16)acc[i][j][3] };
      *(bf16x4*)(base + (size_t)(c0 + col) * DIM + row0) = p;
    }
}

// ---------------- launcher ----------------
extern "C" void kernel_launch(void* const* d_in, const int* in_sizes, int n_in,
                              void* d_out, int out_size, void* d_ws, size_t ws_size,
                              hipStream_t stream) {
  const float* x        = (const float*)d_in[0];
  const float* Mf_prev  = (const float*)d_in[1];
  const float* Ms_prev  = (const float*)d_in[2];
  const float* Wq       = (const float*)d_in[3];
  const float* Wk       = (const float*)d_in[4];
  const float* Wv       = (const float*)d_in[5];
  const float* Wo       = (const float*)d_in[6];
  const float* Wbil     = (const float*)d_in[7];
  const float* fast_slope = (const float*)d_in[8];
  const float* slow_slope = (const float*)d_in[9];
  const float* inter_fast = (const float*)d_in[10];
  const float* inter_slow = (const float*)d_in[11];
  const float* S_fast   = (const float*)d_in[12];
  const float* S_slow   = (const float*)d_in[13];
  const float* f1w      = (const float*)d_in[14];
  const float* f1b      = (const float*)d_in[15];
  const float* f2w      = (const float*)d_in[16];
  const float* f2b      = (const float*)d_in[17];

  char* ws = (char*)d_ws;
  bf16*  xb       = (bf16*)(ws);                    // [0,64Mi) -- alive until final GEMM
  // [64,128Mi): kn (64Mi) -> partials (64Mi) -> W2t [64,96Mi) + Wcombt [96,128Mi)
  bf16*  kn       = (bf16*)(ws + 67108864);
  float* partials = (float*)(ws + 67108864);
  bf16*  W2t      = (bf16*)(ws + 67108864);
  bf16*  Wcombt   = (bf16*)(ws + 100663296);
  bf16*  Wqb      = (bf16*)(ws + 134217728);        // 8 MiB each
  bf16*  Wtk      = (bf16*)(ws + 142606336);
  bf16*  Wtv      = (bf16*)(ws + 150994944);
  bf16*  Wto      = (bf16*)(ws + 159383552);
  bf16*  Wbt      = (bf16*)(ws + 167772160);        // 512 KiB
  float* rbuf     = (float*)(ws + 168296448);       // 256 KiB
  bf16*  Mb       = (bf16*)(ws + 168558592);        // 2 MiB
  float* xm       = (float*)(ws + 170655744);       // 32 KiB
  float* h1raw    = (float*)(ws + 170688512);       // 16 KiB

  float* out  = (float*)d_out;
  float* MfO  = out + 33554432;
  float* MsO  = MfO + 1048576;
  float* psiO = MsO + 1048576;
  // kts/vt live in the (not-yet-written) out region: 2 x 64 MiB
  bf16* kts = (bf16*)d_out;
  bf16* vt  = kts + 33554432;

  // conversions / small precompute
  conv_bf16<<<dim3(BN * DIM / 1024), 256, 0, stream>>>(x, xb);
  conv_bf16<<<dim3(DIM * DIM / 1024), 256, 0, stream>>>(Wq, Wqb);
  tconv3<<<dim3(64, 64, 3), dim3(32, 8), 0, stream>>>(Wk, Wv, Wo, Wtk, Wtv, Wto);
  tconvWb<<<dim3(4, 4, NH), dim3(32, 8), 0, stream>>>(Wbil, Wbt);
  rweights<<<dim3(16, 16), 256, 0, stream>>>(fast_slope, slow_slope, rbuf);

  // psi path
  zero_f32<<<dim3(48), 256, 0, stream>>>(xm, BATCH * DIM + BATCH * (DIM/2));
  mean_part<<<dim3(4, 16, 4), 256, 0, stream>>>(xb, xm);
  mlp1<<<dim3(4, 4, 8), 256, 0, stream>>>(xm, f1w, h1raw);
  mlp2<<<dim3(1), 64, 0, stream>>>(h1raw, f1b, f2w, f2b, psiO);

  // projections on the 256x256 pipelined engine
  gemm256<2><<<dim3(8, 64), 512, 0, stream>>>(xb, DIM, Wtv, DIM, vt, 0, DIM);
  gemm256<5><<<dim3(8, 64), 512, 0, stream>>>(xb, DIM, Wtk, DIM, kn, DIM, DIM);

  // resonance + k_mod + slow-weighted transposed store (consumes kn before partials overlay)
  res_fuse<<<dim3(32, 64), 256, 0, stream>>>(kn, Wbt, slow_slope, kts);

  // decayed outer products (split-K = 8)
  mcurr<<<dim3(8, 64), 256, 0, stream>>>(kts, vt, rbuf, partials);

  // M update + (I+S)@M + psi blend -> Mb[dk][dv]
  finalize<<<dim3(64, 4), 256, 0, stream>>>(partials, Mf_prev, Ms_prev, inter_fast,
                                            inter_slow, S_fast, S_slow, psiO,
                                            MfO, MsO, Mb);

  // W2t[b][c][hdk] = (Mb_blend @ Wo_head)^T   (overlays dead partials)
  w2_gemm<<<dim3(16, 64), 256, 0, stream>>>(Mb, Wto, W2t);

  // Wcombt[b][c][d] = sum_hdk W2t[b][c][hdk] * Wq[d][hdk]   (4 batches x 2048^2, MODE 4)
  gemm256<4><<<dim3(8, 32), 512, 0, stream>>>(W2t, DIM, Wqb, DIM, Wcombt, DIM, DIM);

  // out = x @ Wcomb[b]  (f32; overwrites kts/vt which are dead)
  gemm256<3><<<dim3(8, 64), 512, 0, stream>>>(xb, DIM, Wcombt, DIM, out, DIM, DIM);
}

// Round 3
// 1130.929 us; speedup vs baseline: 1.0895x; 1.0059x over previous
//
#include <hip/hip_runtime.h>
#include <math.h>

typedef __bf16 bf16;
typedef __attribute__((ext_vector_type(8))) __bf16 bf16x8;
typedef __attribute__((ext_vector_type(4))) __bf16 bf16x4;
typedef __attribute__((ext_vector_type(2))) __bf16 bf16x2;
typedef __attribute__((ext_vector_type(4))) float f32x4;

#define DIM 2048
#define NH 16
#define DKK 128
#define BATCH 4
#define SEQ 4096
#define BN (BATCH*SEQ)
#define INV_SQRT_DK 0.08838834764831845f

#define MFMA16(a,b,c) __builtin_amdgcn_mfma_f32_16x16x32_bf16((a),(b),(c),0,0,0)

#define GLDS(gp, lp) __builtin_amdgcn_global_load_lds( \
    (const __attribute__((address_space(1))) void*)(gp), \
    (__attribute__((address_space(3))) void*)(lp), 16, 0, 0)

// stage a 128x64 bf16 tile (row stride ld in global) into LDS (stride 64,
// chunk-XOR swizzle). Wave w stages rows [w*16, w*16+16). 2 GLDS per thread.
__device__ inline void stage_half(const bf16* __restrict__ g, int ld,
                                  bf16* lds, int lane, int wave) {
  const int rl = lane >> 3;                      // 0..7 row within 8-row group
  const int gc = ((lane & 7) ^ (rl & 7)) << 3;   // swizzled source chunk (elements)
  const bf16* gp = g + (size_t)(wave * 16 + rl) * ld + gc;
  GLDS(gp,                  lds + (wave * 16) * 64);
  GLDS(gp + (size_t)8 * ld, lds + (wave * 16 + 8) * 64);
}

// stage a (32*nwaves)x64 tile (4 GLDS/thread) -- used by the 4-wave kernels
__device__ inline void stage_tile(const bf16* __restrict__ g, int ld,
                                  bf16* lds, int lane, int wave) {
  const int rl = lane >> 3;
  const int gc = ((lane & 7) ^ (rl & 7)) << 3;
  const bf16* gp = g + (size_t)(wave * 32 + rl) * ld + gc;
#pragma unroll
  for (int t = 0; t < 4; ++t)
    GLDS(gp + (size_t)(t * 8) * ld, lds + (wave * 32 + t * 8) * 64);
}

// read 8 consecutive (global-k) elements for row r at global chunk kc from a swizzled 64-stride tile
__device__ inline bf16x8 frag8(const bf16* lds, int r, int kc) {
  return *(const bf16x8*)(lds + r * 64 + (((kc ^ (r & 7)) << 3)));
}

// scalar element address in swizzled 64-stride tile
__device__ inline int sq64(int r, int c) {
  return r * 64 + ((((c >> 3) ^ (r & 7)) << 3) | (c & 7));
}

__device__ inline float fast_exp(float x) { return __expf(x); }
__device__ inline float fast_tanh(float x) {
  float e2 = __expf(2.f * x);
  return 1.f - 2.f / (e2 + 1.f);
}

// ---------------- conversion kernels ----------------
__global__ __launch_bounds__(256) void conv_bf16(const float* __restrict__ x,
                                                 bf16* __restrict__ y) {
  int i = (blockIdx.x * 256 + threadIdx.x) * 4;
  float4 v = *(const float4*)(x + i);
  bf16x4 o = { (bf16)v.x, (bf16)v.y, (bf16)v.z, (bf16)v.w };
  *(bf16x4*)(y + i) = o;
}

// 3 fused 2048x2048 transposes selected by blockIdx.z (Wk, Wv, Wo)
__global__ __launch_bounds__(256) void tconv3(const float* W0, const float* W1,
                                              const float* W2,
                                              bf16* O0, bf16* O1, bf16* O2) {
  __shared__ float tile[32][33];
  const float* Wp; bf16* Op;
  switch (blockIdx.z) {
    case 0: Wp = W0; Op = O0; break;
    case 1: Wp = W1; Op = O1; break;
    default: Wp = W2; Op = O2; break;
  }
  int c0 = blockIdx.x * 32, r0 = blockIdx.y * 32;
  int tx = threadIdx.x, ty = threadIdx.y;  // (32,8)
#pragma unroll
  for (int i = 0; i < 4; ++i)
    tile[ty + i*8][tx] = Wp[(size_t)(r0 + ty + i*8) * DIM + c0 + tx];
  __syncthreads();
#pragma unroll
  for (int i = 0; i < 4; ++i)
    Op[(size_t)(c0 + ty + i*8) * DIM + r0 + tx] = (bf16)tile[tx][ty + i*8];
}

// per-head 128x128 transpose for W_bilinear
__global__ __launch_bounds__(256) void tconvWb(const float* __restrict__ W,
                                               bf16* __restrict__ Wt) {
  __shared__ float tile[32][33];
  const float* Wp = W + (size_t)blockIdx.z * DKK * DKK;
  bf16* Wtp = Wt + (size_t)blockIdx.z * DKK * DKK;
  int c0 = blockIdx.x * 32, r0 = blockIdx.y * 32;
  int tx = threadIdx.x, ty = threadIdx.y;
#pragma unroll
  for (int i = 0; i < 4; ++i)
    tile[ty + i*8][tx] = Wp[(size_t)(r0 + ty + i*8) * DKK + c0 + tx];
  __syncthreads();
#pragma unroll
  for (int i = 0; i < 4; ++i)
    Wtp[(size_t)(c0 + ty + i*8) * DKK + r0 + tx] = (bf16)tile[tx][ty + i*8];
}

// rbuf[h][n] = exp((fs[h]-ss[h])*(n-(SEQ-1)))
__global__ __launch_bounds__(256) void rweights(const float* __restrict__ fs,
                                                const float* __restrict__ ss,
                                                float* __restrict__ rbuf) {
  int n = blockIdx.x * 256 + threadIdx.x;
  int h = blockIdx.y;
  rbuf[h * SEQ + n] = fast_exp((fs[h] - ss[h]) * (float)(n - (SEQ - 1)));
}

// ---------------- mean + MLP (psi) ----------------
__global__ void zero_f32(float* p, int n) {
  int i = blockIdx.x * 256 + threadIdx.x;
  if (i < n) p[i] = 0.f;
}

__global__ __launch_bounds__(256) void mean_part(const bf16* __restrict__ xb,
                                                 float* __restrict__ xm) {
  int d0 = (blockIdx.x * 256 + threadIdx.x) * 2;
  int b = blockIdx.z;
  const bf16* xp = xb + ((size_t)b * SEQ + (size_t)blockIdx.y * 256) * DIM + d0;
  float s0 = 0.f, s1 = 0.f;
#pragma unroll 8
  for (int n = 0; n < 256; ++n) {
    bf16x2 v = *(const bf16x2*)(xp + (size_t)n * DIM);
    s0 += (float)v[0]; s1 += (float)v[1];
  }
  atomicAdd(&xm[b * DIM + d0], s0);
  atomicAdd(&xm[b * DIM + d0 + 1], s1);
}

// partial dot over k-split; h1raw accumulates raw (unscaled) sums
__global__ __launch_bounds__(256) void mlp1(const float* __restrict__ xm,
                                            const float* __restrict__ f1w,
                                            float* __restrict__ h1raw) {
  int j = blockIdx.x * 256 + threadIdx.x;   // 0..1023
  int b = blockIdx.y;
  int k0 = blockIdx.z * 256;
  const float* xmb = xm + b * DIM + k0;
  const float* w = f1w + (size_t)k0 * (DIM/2) + j;
  float s = 0.f;
#pragma unroll 4
  for (int k = 0; k < 256; ++k) s += xmb[k] * w[(size_t)k * (DIM/2)];
  atomicAdd(&h1raw[b * (DIM/2) + j], s);
}

__global__ void mlp2(const float* __restrict__ h1raw,
                     const float* __restrict__ f1b,
                     const float* __restrict__ f2w,
                     const float* __restrict__ f2b,
                     float* __restrict__ psi_out) {
  int t = threadIdx.x;  // 64 threads
  int b = t >> 4, h = t & 15;
  float s = f2b[h];
  for (int k = 0; k < DIM/2; ++k) {
    float hv = h1raw[b * (DIM/2) + k] * (1.f / (float)SEQ) + f1b[k];
    hv = hv / (1.f + fast_exp(-hv));          // silu
    s += hv * f2w[k * NH + h];
  }
  psi_out[t] = 1.f / (1.f + fast_exp(-s));    // sigmoid
}

// ---------------- 256x256 8-phase GEMM: C(MxN) = A(MxK) @ Bt(NxK)^T ----------------
// m201-style schedule. 8 waves, BK=64, 2x double-buffered LDS in 128x64 halves.
// Per K-tile: 4 phases, each = {ds_read new frags, stage 1 half-tile, barrier,
// lgkmcnt(0)+sched_barrier, setprio(1), 16 MFMA (one 128x128 C-quadrant x K=64),
// setprio(0), barrier}. Quadrant order: (A0,B0)->(A0,B1)->(A1,B1)->(A1,B0).
// Stage schedule: p0->A1(t+1), p1->B0(t+1), p2->A0(t+2) [cur buf: A0 reads done
// at p0], p3->B1(t+2) [cur buf: B1 reads done at p1]. One s_waitcnt vmcnt(4)
// per K-tile at end of p3 (2 half-tiles stay in flight across the boundary).
// MODE 2: bf16 transposed per-head store (vt).
// MODE 3: f32 normal out, Bt per-batch (+= (m0>>12)*DIM*DIM)  [final: out = x @ Wcomb[b]]
// MODE 4: bf16 normal out, A and C per-batch (2048 rows each)  [Wcombt[b] = W2t[b] @ Wq^T]
// MODE 5: bf16 normal out (row-major MxN)                      [kn = x @ Wk]
template<int MODE>
__global__ __launch_bounds__(512, 2) void gemm256(const bf16* __restrict__ A, int lda,
                                                  const bf16* __restrict__ Bt, int ldb,
                                                  void* __restrict__ Cv, int ldc, int K) {
  __shared__ bf16 smem[65536];   // A: [2buf][2half][128x64] | B same = 128 KiB
  const int tid = threadIdx.x;
  const int lane = tid & 63;
  const int wave = tid >> 6;          // 0..7
  const int quad = lane >> 4;
  const int l15 = lane & 15;
  const int wr2 = wave >> 2;          // 0..1 : 64-row slice inside quadrant
  const int wc2 = wave & 3;           // 0..3 : 32-col slice inside quadrant
  const size_t m0 = (size_t)blockIdx.y * 256;
  const size_t n0 = (size_t)blockIdx.x * 256;
  const bf16* Ap = A;
  const bf16* Bp = Bt;
  size_t mrow = m0;
  size_t cbat = 0;
  if (MODE == 3) Bp += (size_t)(m0 >> 12) * DIM * DIM;
  if (MODE == 4) {
    size_t b = m0 >> 11;              // 2048 rows per batch
    Ap += b * (size_t)DIM * DIM;
    cbat = b * (size_t)DIM * DIM;
    mrow = m0 & 2047;
  }
  const bf16* Arow = Ap + mrow * (size_t)lda;
  const bf16* Brow = Bp + n0 * (size_t)ldb;
  const int NT = K >> 6;

  // stage half h (0/1) of K-tile tt (A or B side), guarded
#define STA(tt, h) do { if ((tt) < NT) \
    stage_half(Arow + (size_t)((h) * 128) * lda + (tt) * 64, lda, \
               smem + ((tt) & 1) * 16384 + (h) * 8192, lane, wave); } while (0)
#define STB(tt, h) do { if ((tt) < NT) \
    stage_half(Brow + (size_t)((h) * 128) * ldb + (tt) * 64, ldb, \
               smem + 32768 + ((tt) & 1) * 16384 + (h) * 8192, lane, wave); } while (0)
#define WAIT_LGKM() do { \
    asm volatile("s_waitcnt lgkmcnt(0)" ::: "memory"); \
    __builtin_amdgcn_sched_barrier(0); } while (0)

  f32x4 acc[2][2][4][2] = {};   // [qa][qb][i][j]
  // prologue: A0(0) B0(0) B1(0) A1(0) A0(1) B1(1) -> 12 loads, keep last 4 in flight
  STA(0, 0); STB(0, 0); STB(0, 1); STA(0, 1); STA(1, 0); STB(1, 1);
  asm volatile("s_waitcnt vmcnt(4)\n\ts_barrier" ::: "memory");

  for (int t = 0; t < NT; ++t) {
    const int cur = t & 1;
    const bf16* sA = smem + cur * 16384;
    const bf16* sB = smem + 32768 + cur * 16384;
    bf16x8 a0[4][2], a1[4][2], b0[2][2], b1[2][2];

    // ---- phase 0: Q(A0,B0); stage A1(t+1) ----
#pragma unroll
    for (int i = 0; i < 4; ++i)
#pragma unroll
      for (int kk = 0; kk < 2; ++kk)
        a0[i][kk] = frag8(sA, wr2 * 64 + i * 16 + l15, kk * 4 + quad);
#pragma unroll
    for (int j = 0; j < 2; ++j)
#pragma unroll
      for (int kk = 0; kk < 2; ++kk)
        b0[j][kk] = frag8(sB, wc2 * 32 + j * 16 + l15, kk * 4 + quad);
    STA(t + 1, 1);
    asm volatile("s_barrier" ::: "memory");
    WAIT_LGKM();
    __builtin_amdgcn_s_setprio(1);
#pragma unroll
    for (int i = 0; i < 4; ++i)
#pragma unroll
      for (int j = 0; j < 2; ++j) {
        acc[0][0][i][j] = MFMA16(a0[i][0], b0[j][0], acc[0][0][i][j]);
        acc[0][0][i][j] = MFMA16(a0[i][1], b0[j][1], acc[0][0][i][j]);
      }
    __builtin_amdgcn_s_setprio(0);
    asm volatile("s_barrier" ::: "memory");

    // ---- phase 1: Q(A0,B1); stage B0(t+1) ----
#pragma unroll
    for (int j = 0; j < 2; ++j)
#pragma unroll
      for (int kk = 0; kk < 2; ++kk)
        b1[j][kk] = frag8(sB + 8192, wc2 * 32 + j * 16 + l15, kk * 4 + quad);
    STB(t + 1, 0);
    asm volatile("s_barrier" ::: "memory");
    WAIT_LGKM();
    __builtin_amdgcn_s_setprio(1);
#pragma unroll
    for (int i = 0; i < 4; ++i)
#pragma unroll
      for (int j = 0; j < 2; ++j) {
        acc[0][1][i][j] = MFMA16(a0[i][0], b1[j][0], acc[0][1][i][j]);
        acc[0][1][i][j] = MFMA16(a0[i][1], b1[j][1], acc[0][1][i][j]);
      }
    __builtin_amdgcn_s_setprio(0);
    asm volatile("s_barrier" ::: "memory");

    // ---- phase 2: Q(A1,B1); stage A0(t+2) into cur (A0 LDS reads done at p0) ----
#pragma unroll
    for (int i = 0; i < 4; ++i)
#pragma unroll
      for (int kk = 0; kk < 2; ++kk)
        a1[i][kk] = frag8(sA + 8192, wr2 * 64 + i * 16 + l15, kk * 4 + quad);
    STA(t + 2, 0);
    asm volatile("s_barrier" ::: "memory");
    WAIT_LGKM();
    __builtin_amdgcn_s_setprio(1);
#pragma unroll
    for (int i = 0; i < 4; ++i)
#pragma unroll
      for (int j = 0; j < 2; ++j) {
        acc[1][1][i][j] = MFMA16(a1[i][0], b1[j][0], acc[1][1][i][j]);
        acc[1][1][i][j] = MFMA16(a1[i][1], b1[j][1], acc[1][1][i][j]);
      }
    __builtin_amdgcn_s_setprio(0);
    asm volatile("s_barrier" ::: "memory");

    // ---- phase 3: Q(A1,B0) (re-read B0); stage B1(t+2) into cur ----
#pragma unroll
    for (int j = 0; j < 2; ++j)
#pragma unroll
      for (int kk = 0; kk < 2; ++kk)
        b0[j][kk] = frag8(sB, wc2 * 32 + j * 16 + l15, kk * 4 + quad);
    STB(t + 2, 1);
    asm volatile("s_barrier" ::: "memory");
    WAIT_LGKM();
    __builtin_amdgcn_s_setprio(1);
#pragma unroll
    for (int i = 0; i < 4; ++i)
#pragma unroll
      for (int j = 0; j < 2; ++j) {
        acc[1][0][i][j] = MFMA16(a1[i][0], b0[j][0], acc[1][0][i][j]);
        acc[1][0][i][j] = MFMA16(a1[i][1], b0[j][1], acc[1][0][i][j]);
      }
    __builtin_amdgcn_s_setprio(0);
    // tile-boundary wait: tile t+1's 4 halves staged at (t-1):p2,(t-1):p3,t:p0,t:p1
    // must retire; the 2 newest (t:p2,t:p3 -> tile t+2 halves) may stay in flight.
    if (t < NT - 2)       asm volatile("s_waitcnt vmcnt(4)" ::: "memory");
    else if (t == NT - 2) asm volatile("s_waitcnt vmcnt(0)" ::: "memory");
    asm volatile("s_barrier" ::: "memory");
  }
#undef STA
#undef STB
#undef WAIT_LGKM

  // ---------------- epilogues ----------------
  if (MODE == 2) {
    // transposed per-head store: vt[(b*NH+h)*DKK + dv][nseq]
    const int bb = (int)(m0 >> 12);
    bf16* vt = (bf16*)Cv;
#pragma unroll
    for (int qa = 0; qa < 2; ++qa)
#pragma unroll
      for (int qb = 0; qb < 2; ++qb)
#pragma unroll
        for (int i = 0; i < 4; ++i)
#pragma unroll
          for (int j = 0; j < 2; ++j) {
            int colg = (int)n0 + qb * 128 + wc2 * 32 + j * 16 + l15;
            int h = colg >> 7, dv = colg & 127;
            int nb = (int)(m0 & 4095) + qa * 128 + wr2 * 64 + i * 16 + quad * 4;
            f32x4 a = acc[qa][qb][i][j];
            bf16x4 p = { (bf16)a[0], (bf16)a[1], (bf16)a[2], (bf16)a[3] };
            *(bf16x4*)(vt + ((size_t)(bb * NH + h) * DKK + dv) * SEQ + nb) = p;
          }
  } else {
#pragma unroll
    for (int qa = 0; qa < 2; ++qa)
#pragma unroll
      for (int qb = 0; qb < 2; ++qb)
#pragma unroll
        for (int i = 0; i < 4; ++i)
#pragma unroll
          for (int j = 0; j < 2; ++j) {
            size_t col = n0 + qb * 128 + wc2 * 32 + j * 16 + l15;
            size_t row = mrow + qa * 128 + wr2 * 64 + i * 16 + quad * 4;
            f32x4 a = acc[qa][qb][i][j];
#pragma unroll
            for (int r = 0; r < 4; ++r) {
              if (MODE == 3) ((float*)Cv)[(row + r) * ldc + col] = a[r];
              else           ((bf16*)Cv)[cbat + (row + r) * ldc + col] = (bf16)a[r];
            }
          }
  }
}

// ---------------- resonance + k_mod + transposed slow-weighted store ----------------
// R[n][e] = sum_d kn[b,n][h*128+d] * Wbt[h][e][d]   (K=128, per (bh, n-tile of 128))
// kts[(bh)*DKK + e][n] = kn[n][e] * (1+0.5*tanh(R[n][e])) * inv_sqrt_dk * exp(ss*(n-(SEQ-1)))
__global__ __launch_bounds__(256) void res_fuse(const bf16* __restrict__ kn,
                                                const bf16* __restrict__ Wbt,
                                                const float* __restrict__ slow_slope,
                                                bf16* __restrict__ kts) {
  __shared__ bf16 sA2[2][8192];   // both 64-chunks of the kn tile (kept for epilogue)
  __shared__ bf16 sB[8192];
  const int tid = threadIdx.x;
  const int lane = tid & 63;
  const int wave = tid >> 6;
  const int quad = lane >> 4;
  const int l15 = lane & 15;
  const int wm = (wave & 1) * 64;
  const int wn = (wave >> 1) * 64;
  const int nt = blockIdx.x;              // 0..31 (n-tile within batch)
  const int bh = blockIdx.y;              // 0..63
  const int h = bh & (NH - 1), b = bh >> 4;
  const bf16* Ap = kn + ((size_t)b * SEQ + (size_t)nt * 128) * DIM + h * DKK;
  const bf16* Bp = Wbt + (size_t)h * DKK * DKK;
  const float ss = slow_slope[h];
  f32x4 acc[4][4] = {};
#pragma unroll
  for (int c = 0; c < 2; ++c) {
    stage_tile(Ap + c * 64, DIM, sA2[c], lane, wave);
    stage_tile(Bp + c * 64, DKK, sB, lane, wave);
    __syncthreads();
#pragma unroll
    for (int kk = 0; kk < 2; ++kk) {
      const int kc = kk * 4 + quad;
      bf16x8 af[4], bfr[4];
#pragma unroll
      for (int i = 0; i < 4; ++i) af[i] = frag8(sA2[c], wm + i*16 + l15, kc);
#pragma unroll
      for (int j = 0; j < 4; ++j) bfr[j] = frag8(sB, wn + j*16 + l15, kc);
#pragma unroll
      for (int i = 0; i < 4; ++i)
#pragma unroll
        for (int j = 0; j < 4; ++j)
          acc[i][j] = MFMA16(af[i], bfr[j], acc[i][j]);
    }
    __syncthreads();
  }
  float wsv[4][4];
#pragma unroll
  for (int i = 0; i < 4; ++i)
#pragma unroll
    for (int r = 0; r < 4; ++r) {
      int ng = nt * 128 + wm + i*16 + quad*4 + r;
      wsv[i][r] = fast_exp(ss * (float)(ng - (SEQ - 1)));
    }
#pragma unroll
  for (int i = 0; i < 4; ++i)
#pragma unroll
    for (int j = 0; j < 4; ++j) {
      int e = wn + j*16 + l15;
      const bf16* sAe = sA2[e >> 6];
      int ec = e & 63;
      bf16x4 p;
#pragma unroll
      for (int r = 0; r < 4; ++r) {
        int nl = wm + i*16 + quad*4 + r;
        float kv = (float)sAe[sq64(nl, ec)];
        float res = fast_tanh(acc[i][j][r]);
        p[r] = (bf16)(kv * (1.f + 0.5f * res) * INV_SQRT_DK * wsv[i][r]);
      }
      *(bf16x4*)(kts + ((size_t)bh * DKK + e) * SEQ + nt * 128 + wm + i*16 + quad*4) = p;
    }
}

// ---------------- mcurr: partials[s][bh][{fast,slow}] = Kt(diag w)V over n-split ----------------
__global__ __launch_bounds__(256) void mcurr(const bf16* __restrict__ kts,
                                             const bf16* __restrict__ vt,
                                             const float* __restrict__ rbuf,
                                             float* __restrict__ partials) {
  __shared__ bf16 sK[128 * 64];
  __shared__ bf16 sV[128 * 64];
  const int tid = threadIdx.x;
  const int lane = tid & 63;
  const int wave = tid >> 6;
  const int quad = lane >> 4;
  const int wm = (wave & 1) * 64, wn = (wave >> 1) * 64;
  const int s = blockIdx.x;          // 0..7
  const int bh = blockIdx.y;         // 0..63
  const int h = bh & (NH - 1);
  const bf16* Ap = kts + (size_t)bh * DKK * SEQ;
  const bf16* Bp = vt + (size_t)bh * DKK * SEQ;
  const float* rp = rbuf + (size_t)h * SEQ;
  f32x4 accF[4][4] = {}, accS[4][4] = {};
  for (int k0 = s * 512; k0 < s * 512 + 512; k0 += 64) {
    stage_tile(Ap + k0, SEQ, sK, lane, wave);
    stage_tile(Bp + k0, SEQ, sV, lane, wave);
    __syncthreads();
#pragma unroll
    for (int kk = 0; kk < 2; ++kk) {
      const int kc = kk * 4 + quad;
      const int kn_ = k0 + kc * 8;
      float rv[8];
      *(f32x4*)rv       = *(const f32x4*)(rp + kn_);
      *(f32x4*)(rv + 4) = *(const f32x4*)(rp + kn_ + 4);
      bf16x8 afS[4], afF[4], bfv[4];
#pragma unroll
      for (int i = 0; i < 4; ++i) afS[i] = frag8(sK, wm + i*16 + (lane & 15), kc);
#pragma unroll
      for (int j = 0; j < 4; ++j) bfv[j] = frag8(sV, wn + j*16 + (lane & 15), kc);
#pragma unroll
      for (int i = 0; i < 4; ++i)
#pragma unroll
        for (int e = 0; e < 8; ++e)
          afF[i][e] = (bf16)((float)afS[i][e] * rv[e]);
#pragma unroll
      for (int i = 0; i < 4; ++i)
#pragma unroll
        for (int j = 0; j < 4; ++j) {
          accS[i][j] = MFMA16(afS[i], bfv[j], accS[i][j]);
          accF[i][j] = MFMA16(afF[i], bfv[j], accF[i][j]);
        }
    }
    __syncthreads();
  }
  float* Pf = partials + ((size_t)(s * 64 + bh) * 2 + 0) * (DKK * DKK);
  float* Ps = partials + ((size_t)(s * 64 + bh) * 2 + 1) * (DKK * DKK);
#pragma unroll
  for (int i = 0; i < 4; ++i)
#pragma unroll
    for (int j = 0; j < 4; ++j) {
      int col = wn + j*16 + (lane & 15);
      int row = wm + i*16 + quad * 4;
#pragma unroll
      for (int r = 0; r < 4; ++r) {
        Pf[(row + r) * DKK + col] = accF[i][j][r];
        Ps[(row + r) * DKK + col] = accS[i][j][r];
      }
    }
}

// ---------------- finalize: M update, (I+S)@M, blend -> Mb (normal order, bf16) ----------------
__global__ __launch_bounds__(256) void finalize(const float* __restrict__ partials,
                                                const float* __restrict__ Mf_prev,
                                                const float* __restrict__ Ms_prev,
                                                const float* __restrict__ inter_fast,
                                                const float* __restrict__ inter_slow,
                                                const float* __restrict__ S_fast,
                                                const float* __restrict__ S_slow,
                                                const float* __restrict__ psi,
                                                float* __restrict__ Mf_out,
                                                float* __restrict__ Ms_out,
                                                bf16* __restrict__ Mb) {
  __shared__ float sMf[128 * 33];
  __shared__ float sMs[128 * 33];
  const int t = threadIdx.x;
  const int bh = blockIdx.x;
  const int h = bh & (NH - 1);
  const int e0 = blockIdx.y * 32;
  const int el = t & 31;
  const int d0 = t >> 5;  // 0..7
  const float inf_ = inter_fast[h], ins_ = inter_slow[h];
  const size_t mb = (size_t)bh * (DKK * DKK);
#pragma unroll
  for (int i = 0; i < 16; ++i) {
    int d = d0 + 8 * i;
    int g = d * DKK + e0 + el;
    float mf = inf_ * Mf_prev[mb + g];
    float ms = ins_ * Ms_prev[mb + g];
#pragma unroll
    for (int s = 0; s < 8; ++s) {
      mf += partials[((size_t)(s * 64 + bh) * 2 + 0) * (DKK*DKK) + g];
      ms += partials[((size_t)(s * 64 + bh) * 2 + 1) * (DKK*DKK) + g];
    }
    Mf_out[mb + g] = mf;
    Ms_out[mb + g] = ms;
    sMf[d * 33 + el] = mf;
    sMs[d * 33 + el] = ms;
  }
  __syncthreads();
  const float p = psi[bh];
  for (int i = 0; i < 16; ++i) {
    int d = d0 + 8 * i;
    float accf = sMf[d * 33 + el];
    float accs = sMs[d * 33 + el];
    const float* Sf = S_fast + (size_t)h * (DKK*DKK) + (size_t)d * DKK;
    const float* Ss = S_slow + (size_t)h * (DKK*DKK) + (size_t)d * DKK;
    for (int k = 0; k < DKK; ++k) {
      accf += Sf[k] * sMf[k * 33 + el];
      accs += Ss[k] * sMs[k * 33 + el];
    }
    float blend = (1.f - p) * accf + p * accs;
    Mb[mb + (size_t)d * DKK + e0 + el] = (bf16)blend;   // Mb[dk][dv]
  }
}

// ---------------- w2: W2t[b][c][h*128+dk] = sum_dv Mb[b,h][dk,dv] * Wo[h*128+dv][c] ----------------
__global__ __launch_bounds__(256) void w2_gemm(const bf16* __restrict__ Mb,
                                               const bf16* __restrict__ Wto,
                                               bf16* __restrict__ W2t) {
  __shared__ bf16 sA[128 * 64];
  __shared__ bf16 sB[128 * 64];
  const int tid = threadIdx.x;
  const int lane = tid & 63;
  const int wave = tid >> 6;
  const int quad = lane >> 4;
  const int wm = (wave & 1) * 64, wn = (wave >> 1) * 64;
  const int c0 = blockIdx.x * 128;
  const int bh = blockIdx.y;
  const int h = bh & (NH - 1), b = bh >> 4;
  const bf16* Ap = Mb + (size_t)bh * DKK * DKK;
  const bf16* Bp = Wto + (size_t)c0 * DIM + h * DKK;
  f32x4 acc[4][4] = {};
#pragma unroll
  for (int k0 = 0; k0 < DKK; k0 += 64) {
    stage_tile(Ap + k0, DKK, sA, lane, wave);
    stage_tile(Bp + k0, DIM, sB, lane, wave);
    __syncthreads();
#pragma unroll
    for (int kk = 0; kk < 2; ++kk) {
      const int kc = kk * 4 + quad;
      bf16x8 af[4], bfr[4];
#pragma unroll
      for (int i = 0; i < 4; ++i) af[i] = frag8(sA, wm + i*16 + (lane & 15), kc);
#pragma unroll
      for (int j = 0; j < 4; ++j) bfr[j] = frag8(sB, wn + j*16 + (lane & 15), kc);
#pragma unroll
      for (int i = 0; i < 4; ++i)
#pragma unroll
        for (int j = 0; j < 4; ++j)
          acc[i][j] = MFMA16(af[i], bfr[j], acc[i][j]);
    }
    __syncthreads();
  }
  // transposed store: W2t[b] + (c0+col)*DIM + h*128 + row   (pack 4 rows)
  bf16* base = W2t + (size_t)b * DIM * DIM + h * DKK;
#pragma unroll
  for (int i = 0; i < 4; ++i)
#pragma unroll
    for (int j = 0; j < 4; ++j) {
      int col = wn + j*16 + (lane & 15);
      int row0 = wm + i*16 + quad * 4;
      bf16x4 p = { (bf16)acc[i][j][0], (bf16)acc[i][j][1],
                   (bf16)acc[i][j][2], (bf16)acc[i][j][3] };
      *(bf16x4*)(base + (size_t)(c0 + col) * DIM + row0) = p;
    }
}

// ---------------- launcher ----------------
extern "C" void kernel_launch(void* const* d_in, const int* in_sizes, int n_in,
                              void* d_out, int out_size, void* d_ws, size_t ws_size,
                              hipStream_t stream) {
  const float* x        = (const float*)d_in[0];
  const float* Mf_prev  = (const float*)d_in[1];
  const float* Ms_prev  = (const float*)d_in[2];
  const float* Wq       = (const float*)d_in[3];
  const float* Wk       = (const float*)d_in[4];
  const float* Wv       = (const float*)d_in[5];
  const float* Wo       = (const float*)d_in[6];
  const float* Wbil     = (const float*)d_in[7];
  const float* fast_slope = (const float*)d_in[8];
  const float* slow_slope = (const float*)d_in[9];
  const float* inter_fast = (const float*)d_in[10];
  const float* inter_slow = (const float*)d_in[11];
  const float* S_fast   = (const float*)d_in[12];
  const float* S_slow   = (const float*)d_in[13];
  const float* f1w      = (const float*)d_in[14];
  const float* f1b      = (const float*)d_in[15];
  const float* f2w      = (const float*)d_in[16];
  const float* f2b      = (const float*)d_in[17];

  char* ws = (char*)d_ws;
  bf16*  xb       = (bf16*)(ws);                    // [0,64Mi) -- alive until final GEMM
  // [64,128Mi): kn (64Mi) -> partials (64Mi) -> W2t [64,96Mi) + Wcombt [96,128Mi)
  bf16*  kn       = (bf16*)(ws + 67108864);
  float* partials = (float*)(ws + 67108864);
  bf16*  W2t      = (bf16*)(ws + 67108864);
  bf16*  Wcombt   = (bf16*)(ws + 100663296);
  bf16*  Wqb      = (bf16*)(ws + 134217728);        // 8 MiB each
  bf16*  Wtk      = (bf16*)(ws + 142606336);
  bf16*  Wtv      = (bf16*)(ws + 150994944);
  bf16*  Wto      = (bf16*)(ws + 159383552);
  bf16*  Wbt      = (bf16*)(ws + 167772160);        // 512 KiB
  float* rbuf     = (float*)(ws + 168296448);       // 256 KiB
  bf16*  Mb       = (bf16*)(ws + 168558592);        // 2 MiB
  float* xm       = (float*)(ws + 170655744);       // 32 KiB
  float* h1raw    = (float*)(ws + 170688512);       // 16 KiB

  float* out  = (float*)d_out;
  float* MfO  = out + 33554432;
  float* MsO  = MfO + 1048576;
  float* psiO = MsO + 1048576;
  // kts/vt live in the (not-yet-written) out region: 2 x 64 MiB
  bf16* kts = (bf16*)d_out;
  bf16* vt  = kts + 33554432;

  // conversions / small precompute
  conv_bf16<<<dim3(BN * DIM / 1024), 256, 0, stream>>>(x, xb);
  conv_bf16<<<dim3(DIM * DIM / 1024), 256, 0, stream>>>(Wq, Wqb);
  tconv3<<<dim3(64, 64, 3), dim3(32, 8), 0, stream>>>(Wk, Wv, Wo, Wtk, Wtv, Wto);
  tconvWb<<<dim3(4, 4, NH), dim3(32, 8), 0, stream>>>(Wbil, Wbt);
  rweights<<<dim3(16, 16), 256, 0, stream>>>(fast_slope, slow_slope, rbuf);

  // psi path
  zero_f32<<<dim3(48), 256, 0, stream>>>(xm, BATCH * DIM + BATCH * (DIM/2));
  mean_part<<<dim3(4, 16, 4), 256, 0, stream>>>(xb, xm);
  mlp1<<<dim3(4, 4, 8), 256, 0, stream>>>(xm, f1w, h1raw);
  mlp2<<<dim3(1), 64, 0, stream>>>(h1raw, f1b, f2w, f2b, psiO);

  // projections on the 256x256 8-phase engine
  gemm256<2><<<dim3(8, 64), 512, 0, stream>>>(xb, DIM, Wtv, DIM, vt, 0, DIM);
  gemm256<5><<<dim3(8, 64), 512, 0, stream>>>(xb, DIM, Wtk, DIM, kn, DIM, DIM);

  // resonance + k_mod + slow-weighted transposed store (consumes kn before partials overlay)
  res_fuse<<<dim3(32, 64), 256, 0, stream>>>(kn, Wbt, slow_slope, kts);

  // decayed outer products (split-K = 8)
  mcurr<<<dim3(8, 64), 256, 0, stream>>>(kts, vt, rbuf, partials);

  // M update + (I+S)@M + psi blend -> Mb[dk][dv]
  finalize<<<dim3(64, 4), 256, 0, stream>>>(partials, Mf_prev, Ms_prev, inter_fast,
                                            inter_slow, S_fast, S_slow, psiO,
                                            MfO, MsO, Mb);

  // W2t[b][c][hdk] = (Mb_blend @ Wo_head)^T   (overlays dead partials)
  w2_gemm<<<dim3(16, 64), 256, 0, stream>>>(Mb, Wto, W2t);

  // Wcombt[b][c][d] = sum_hdk W2t[b][c][hdk] * Wq[d][hdk]   (4 batches x 2048^2, MODE 4)
  gemm256<4><<<dim3(8, 32), 512, 0, stream>>>(W2t, DIM, Wqb, DIM, Wcombt, DIM, DIM);

  // out = x @ Wcomb[b]  (f32; overwrites kts/vt which are dead)
  gemm256<3><<<dim3(8, 64), 512, 0, stream>>>(xb, DIM, Wcombt, DIM, out, DIM, DIM);
}